// Round 2
// baseline (158.587 us; speedup 1.0000x reference)
//
#include <hip/hip_runtime.h>
#include <hip/hip_bf16.h>

#define DEPTH   6
#define NLEAF   64          // 2^DEPTH
#define BATCH   1024
#define DIM     256
#define NTREES  512
#define UNITS   16

#define BTILE   128         // batch rows per block
#define TTILE   8           // trees per block
#define KCHUNK  32
#define NTILES  (NTREES / TTILE)   // 64
#define BBLK    (BATCH / BTILE)    // 8
#define NDCOLS  (TTILE * DEPTH)    // 48 fv columns per block

// ---------------- ws layout (floats) ----------------
// selp    : DIM*NTREES*DEPTH  = 786432   (selectors * invtemp, layout (i, n, d))
// invtemp : NTREES*DEPTH      = 3072
// thrp    : NTREES*DEPTH      = 3072     (thresholds * invtemp)
// partial : NTILES*BATCH*UNITS= 1048576
#define WS_SELP    0
#define WS_INVTEMP (WS_SELP + DIM*NTREES*DEPTH)
#define WS_THRP    (WS_INVTEMP + NTREES*DEPTH)
#define WS_PARTIAL (WS_THRP + NTREES*DEPTH)

// ---------------------------------------------------------------------------
// Kernel 0: invtemp = exp(-log_temp); thr' = thr * invtemp
// ---------------------------------------------------------------------------
__global__ void prep_small(const float* __restrict__ thr,
                           const float* __restrict__ lt,
                           float* __restrict__ invtemp,
                           float* __restrict__ thrp) {
    int i = blockIdx.x * 256 + threadIdx.x;
    if (i < NTREES * DEPTH) {
        float it = __expf(-lt[i]);
        invtemp[i] = it;
        thrp[i]    = thr[i] * it;
    }
}

// ---------------------------------------------------------------------------
// Kernel 1: sparsemax over depth axis of (dim, n_trees, depth), scaled by invtemp
// Mirrors reference semantics exactly (sum-of-support count, cs at k-1).
// ---------------------------------------------------------------------------
__global__ void prep_sparsemax(const float* __restrict__ fsl,
                               const float* __restrict__ invtemp,
                               float* __restrict__ selp) {
    int t = blockIdx.x * 256 + threadIdx.x;   // 0 .. DIM*NTREES-1
    int i = t >> 9;                            // dim index (NTREES==512)
    int n = t & (NTREES - 1);
    int base = (i * NTREES + n) * DEPTH;

    float zv[DEPTH], zs[DEPTH];
#pragma unroll
    for (int d = 0; d < DEPTH; ++d) { zv[d] = fsl[base + d]; zs[d] = zv[d]; }

    // descending bubble sort, 15 compare-swaps, fully static
#pragma unroll
    for (int p = 0; p < DEPTH - 1; ++p) {
#pragma unroll
        for (int j = 0; j < DEPTH - 1 - p; ++j) {
            float a = zs[j], b = zs[j + 1];
            zs[j]     = fmaxf(a, b);
            zs[j + 1] = fminf(a, b);
        }
    }

    float cs[DEPTH];
    cs[0] = zs[0];
#pragma unroll
    for (int d = 1; d < DEPTH; ++d) cs[d] = cs[d - 1] + zs[d];

    int k = 0;
#pragma unroll
    for (int d = 0; d < DEPTH; ++d)
        if (zs[d] * (float)(d + 1) > cs[d] - 1.0f) k++;

    float csk = cs[0];
#pragma unroll
    for (int d = 0; d < DEPTH; ++d) csk = (k - 1 == d) ? cs[d] : csk;

    float tau = (csk - 1.0f) / (float)k;

#pragma unroll
    for (int d = 0; d < DEPTH; ++d) {
        float it = invtemp[n * DEPTH + d];
        selp[base + d] = fmaxf(zv[d] - tau, 0.0f) * it;
    }
}

// ---------------------------------------------------------------------------
// Kernel 2: fused  fv-GEMM -> gates -> leaf probs -> response matvec
// grid (NTILES, BBLK), 256 threads
// ---------------------------------------------------------------------------
__global__ __launch_bounds__(256)
void main_kernel(const float* __restrict__ x,
                 const float* __restrict__ selp,
                 const float* __restrict__ thrp,
                 const float* __restrict__ resp,
                 float* __restrict__ partial) {
    __shared__ union SM {
        struct {
            float x[KCHUNK][132];     // transposed x tile, pad 132: aligned b128, spread banks
            float sel[KCHUNK][TTILE * 8]; // per-tree padded to 8 for aligned b128+b64
        } a;
        float gates[NDCOLS][BTILE];   // [n*6+d][b]
    } sm;

    const int tid   = threadIdx.x;
    const int ntile = blockIdx.x;                 // 0..63
    const int btile = blockIdx.y;                 // 0..7
    const int b0    = btile * BTILE;
    const int col0  = ntile * NDCOLS;             // first fv column (trees contiguous)
    const int ng0   = ntile * TTILE;              // first global tree

    // ---- stage A: tl[128][48] = x(128x256) * sel'(256x48) - thr' ----
    const int tn = tid & (TTILE - 1);             // tree within tile
    const int tb = tid >> 3;                      // 0..31, owns 4 batch rows

    float acc[4][DEPTH];
#pragma unroll
    for (int bb = 0; bb < 4; ++bb)
#pragma unroll
        for (int d = 0; d < DEPTH; ++d) acc[bb][d] = 0.0f;

    for (int kc = 0; kc < DIM; kc += KCHUNK) {
        // x tile: 128x32, transposed into LDS [k][b]
#pragma unroll
        for (int i = 0; i < 16; ++i) {
            int e = tid + i * 256;                // 0..4095
            int b = e >> 5;
            int k = e & 31;
            sm.a.x[k][b] = x[(b0 + b) * DIM + kc + k];
        }
        // sel tile: 32 k-rows x 48 cols, padded per tree to 8
#pragma unroll
        for (int i = 0; i < 6; ++i) {
            int e = tid + i * 256;                // 0..1535
            int k = e / NDCOLS;
            int c = e - k * NDCOLS;
            int tt = c / DEPTH;
            int d  = c - tt * DEPTH;
            sm.a.sel[k][tt * 8 + d] = selp[(kc + k) * (NTREES * DEPTH) + col0 + c];
        }
        __syncthreads();

#pragma unroll 8
        for (int k = 0; k < KCHUNK; ++k) {
            float4 xv = *(const float4*)&sm.a.x[k][tb * 4];
            float4 s0 = *(const float4*)&sm.a.sel[k][tn * 8];
            float2 s1 = *(const float2*)&sm.a.sel[k][tn * 8 + 4];
            float xb[4] = {xv.x, xv.y, xv.z, xv.w};
            float sv[DEPTH] = {s0.x, s0.y, s0.z, s0.w, s1.x, s1.y};
#pragma unroll
            for (int bb = 0; bb < 4; ++bb)
#pragma unroll
                for (int d = 0; d < DEPTH; ++d)
                    acc[bb][d] = fmaf(xb[bb], sv[d], acc[bb][d]);
        }
        __syncthreads();
    }

    // gates = sparsemoid(tl) into LDS (union overwrites staging buffers — safe post-barrier)
#pragma unroll
    for (int d = 0; d < DEPTH; ++d) {
        float th = thrp[(ng0 + tn) * DEPTH + d];
#pragma unroll
        for (int bb = 0; bb < 4; ++bb) {
            float tl = acc[bb][d] - th;
            float g  = fminf(fmaxf(0.5f * tl + 0.5f, 0.0f), 1.0f);
            sm.gates[tn * DEPTH + d][tb * 4 + bb] = g;
        }
    }
    __syncthreads();

    // ---- stage B: per (b, u-half) across all 8 trees of the tile ----
    const int b  = tid & (BTILE - 1);
    const int uh = __builtin_amdgcn_readfirstlane(tid >> 7);  // wave-uniform 0/1

    float out8[8];
#pragma unroll
    for (int u = 0; u < 8; ++u) out8[u] = 0.0f;

    for (int n = 0; n < TTILE; ++n) {
        float g[DEPTH];
#pragma unroll
        for (int d = 0; d < DEPTH; ++d) g[d] = sm.gates[n * DEPTH + d][b];

        // leaf probabilities: p[c] = prod_d (bit_d(c) ? (1-g_d) : g_d), static unroll
        float p[NLEAF];
        p[0] = 1.0f;
#pragma unroll
        for (int d = 0; d < DEPTH; ++d) {
            int w = 1 << d;
            float gd = g[d], hd = 1.0f - g[d];
#pragma unroll
            for (int c = w - 1; c >= 0; --c) {
                float base = p[c];
                p[c + w] = base * hd;
                p[c]     = base * gd;
            }
        }

        // response matvec: wave-uniform address -> s_load + v_fmac(sgpr)
        const float* rp = resp + (((ng0 + n) * UNITS) + uh * 8) * NLEAF;
#pragma unroll
        for (int u = 0; u < 8; ++u) {
            float a = 0.0f;
#pragma unroll
            for (int c = 0; c < NLEAF; ++c)
                a = fmaf(p[c], rp[u * NLEAF + c], a);
            out8[u] += a;
        }
    }

    float* pp = partial + ((size_t)(ntile * BATCH + b0 + b)) * UNITS + uh * 8;
    float4 w0 = {out8[0], out8[1], out8[2], out8[3]};
    float4 w1 = {out8[4], out8[5], out8[6], out8[7]};
    *(float4*)&pp[0] = w0;
    *(float4*)&pp[4] = w1;
}

// ---------------------------------------------------------------------------
// Kernel 3: reduce over 64 ntile partials, scale by 1/NTREES
// ---------------------------------------------------------------------------
__global__ void reduce_kernel(const float* __restrict__ partial,
                              float* __restrict__ out) {
    int idx = blockIdx.x * 256 + threadIdx.x;   // 0..16383
    float s = 0.0f;
#pragma unroll 8
    for (int nt = 0; nt < NTILES; ++nt)
        s += partial[(size_t)nt * BATCH * UNITS + idx];
    out[idx] = s * (1.0f / (float)NTREES);
}

// ---------------------------------------------------------------------------
extern "C" void kernel_launch(void* const* d_in, const int* in_sizes, int n_in,
                              void* d_out, int out_size, void* d_ws, size_t ws_size,
                              hipStream_t stream) {
    const float* x    = (const float*)d_in[0];
    const float* fsl  = (const float*)d_in[1];
    const float* thr  = (const float*)d_in[2];
    const float* lt   = (const float*)d_in[3];
    const float* resp = (const float*)d_in[4];
    float* out = (float*)d_out;
    float* ws  = (float*)d_ws;

    float* selp    = ws + WS_SELP;
    float* invtemp = ws + WS_INVTEMP;
    float* thrp    = ws + WS_THRP;
    float* partial = ws + WS_PARTIAL;

    prep_small<<<(NTREES * DEPTH + 255) / 256, 256, 0, stream>>>(thr, lt, invtemp, thrp);
    prep_sparsemax<<<(DIM * NTREES) / 256, 256, 0, stream>>>(fsl, invtemp, selp);
    main_kernel<<<dim3(NTILES, BBLK), 256, 0, stream>>>(x, selp, thrp, resp, partial);
    reduce_kernel<<<(BATCH * UNITS) / 256, 256, 0, stream>>>(partial, out);
}